// Round 10
// baseline (405.964 us; speedup 1.0000x reference)
//
#include <hip/hip_runtime.h>
#include <hip/hip_bf16.h>

#define L_ 256
#define H_ 4
#define ROWS 2048
#define NEGV (-4294967295.0f)   // -(2^32)+1 as float

typedef unsigned short us16;

__device__ __forceinline__ float us2f(us16 u){ return __uint_as_float(((unsigned)u)<<16); }
__device__ __forceinline__ us16 f2us(float f){ __hip_bfloat16 h=__float2bfloat16(f); return *(us16*)&h; }

struct KArgs {
    const int *log_seqs, *tmat, *pos_seqs, *neg_seqs;
    const float *item_emb, *posK, *posV, *timeK, *timeV;
    const float *ln1g, *ln1b, *bq, *bk, *bv, *ln2g, *ln2b, *b1, *b2, *lnfg, *lnfb;
    const float *Wq, *Wk, *Wv, *W1, *W2;
    float *qin0, *qin1, *out;
    us16 *wsWT, *tmK, *tmV, *Qb0, *Kb0, *Vb0, *Qb1, *Kb1, *Vb1;
};

// LayerNorm of 8 LDS rows in place; thread t: row t>>5, 4 elems strided 32.
__device__ __forceinline__ void ln_rows(float* sA,
        const float* __restrict__ g, const float* __restrict__ b,
        float* qin_out, int r0, int tid){
    int r=tid>>5, l=tid&31;
    float* x=sA+r*128;
    float x0=x[l],x1=x[l+32],x2=x[l+64],x3=x[l+96];
    float s=x0+x1+x2+x3;
    #pragma unroll
    for(int o=16;o;o>>=1) s+=__shfl_xor(s,o,64);
    float m=s*(1.f/128.f);
    float d0=x0-m,d1=x1-m,d2=x2-m,d3=x3-m;
    float v=d0*d0+d1*d1+d2*d2+d3*d3;
    #pragma unroll
    for(int o=16;o;o>>=1) v+=__shfl_xor(v,o,64);
    float rstd=rsqrtf(v*(1.f/128.f)+1e-8f);
    float y0=d0*rstd*g[l]+b[l];
    float y1=d1*rstd*g[l+32]+b[l+32];
    float y2=d2*rstd*g[l+64]+b[l+64];
    float y3=d3*rstd*g[l+96]+b[l+96];
    x[l]=y0; x[l+32]=y1; x[l+64]=y2; x[l+96]=y3;
    if(qin_out){
        float* q=qin_out+(size_t)(r0+r)*128;
        q[l]=y0; q[l+32]=y1; q[l+64]=y2; q[l+96]=y3;
    }
}

// 2-row x 2-col register tile over K=128 from LDS
__device__ __forceinline__ void gemm2x2(const float* A, const us16* sW,
        int ra, int rb, int c0, float* acc){
    float a00=0,a01=0,a10=0,a11=0;
    const float* Ar=A+ra*128;
    const float* Br=A+rb*128;
    #pragma unroll 8
    for(int k=0;k<128;k++){
        ushort2 wp=*(const ushort2*)(sW+k*128+c0);
        float w0=us2f(wp.x), w1=us2f(wp.y);
        float x0=Ar[k], x1=Br[k];
        a00=fmaf(x0,w0,a00); a01=fmaf(x0,w1,a01);
        a10=fmaf(x1,w0,a10); a11=fmaf(x1,w1,a11);
    }
    acc[0]=a00; acc[1]=a01; acc[2]=a10; acc[3]=a11;
}

// dot of bf16 row (global, contiguous 128) with fp32 LDS row (wave-broadcast)
__device__ __forceinline__ float gemv_wt(const us16* __restrict__ wt, const float* x){
    float acc=0;
    const uint4* W4=(const uint4*)wt;
    #pragma unroll
    for(int c=0;c<16;c++){
        uint4 wv=W4[c];
        const us16* wu=(const us16*)&wv;
        const float* xx=x+c*8;
        acc += xx[0]*us2f(wu[0])+xx[1]*us2f(wu[1])+xx[2]*us2f(wu[2])+xx[3]*us2f(wu[3])
             + xx[4]*us2f(wu[4])+xx[5]*us2f(wu[5])+xx[6]*us2f(wu[6])+xx[7]*us2f(wu[7]);
    }
    return acc;
}

// k_pre: bid<768: embed+LN1+QKV(L0) (8 rows/block, fp32 weights staged->bf16 LDS).
//        bid 768..879: convert+TRANSPOSE 7 tail matrices fp32 -> bf16 wsWT.
//        bid 880..945: convert timeK/timeV tables to bf16.
__global__ __launch_bounds__(256) void k_pre(KArgs a){
    __shared__ __align__(16) char smem[36864];
    int tid=threadIdx.x, bid=blockIdx.x;
    if(bid<768){
        us16* sW=(us16*)smem;
        float* sA=(float*)(smem+32768);
        int m=bid>>8, rg=bid&255, r0=rg*8;
        {   // embed 8 rows
            int rl=tid>>5, c4=tid&31;
            int id=a.log_seqs[r0+rl];
            float4 v=((const float4*)a.item_emb)[id*32+c4];
            float sc = id? 11.3137085f : 0.f;   // sqrt(128), pad-zeroed
            v.x*=sc; v.y*=sc; v.z*=sc; v.w*=sc;
            ((float4*)sA)[tid]=v;
        }
        const float* Wsrc=(m==0)?a.Wq:(m==1)?a.Wk:a.Wv;
        {   // stage fp32 weights -> bf16 LDS
            const float4* src=(const float4*)Wsrc;
            ushort4* dst=(ushort4*)sW;
            #pragma unroll
            for(int j=0;j<16;j++){
                float4 w=src[j*256+tid];
                ushort4 o; o.x=f2us(w.x);o.y=f2us(w.y);o.z=f2us(w.z);o.w=f2us(w.w);
                dst[j*256+tid]=o;
            }
        }
        __syncthreads();
        if(m==0){ ln_rows(sA, a.ln1g, a.ln1b, a.qin0, r0, tid); __syncthreads(); }
        int cp=tid&63, rp=tid>>6, c0=2*cp, ra=2*rp, rb=ra+1;
        float acc[4];
        gemm2x2(sA,sW,ra,rb,c0,acc);
        if(m==0){
            float b0v=a.bq[c0], b1v=a.bq[c0+1];
            ushort2 s0; s0.x=f2us(acc[0]+b0v); s0.y=f2us(acc[1]+b1v);
            ushort2 s1; s1.x=f2us(acc[2]+b0v); s1.y=f2us(acc[3]+b1v);
            *(ushort2*)(a.Qb0+(size_t)(r0+ra)*128+c0)=s0;
            *(ushort2*)(a.Qb0+(size_t)(r0+rb)*128+c0)=s1;
        } else {
            const float* bb=(m==1)?a.bk:a.bv;
            const float* pp=(m==1)?a.posK:a.posV;
            us16* Oo=(m==1)?a.Kb0:a.Vb0;
            int qa=(r0+ra)&255, qb2=(r0+rb)&255;
            float b0v=bb[c0], b1v=bb[c0+1];
            ushort2 s0; s0.x=f2us(acc[0]+b0v+pp[qa*128+c0]);  s0.y=f2us(acc[1]+b1v+pp[qa*128+c0+1]);
            ushort2 s1; s1.x=f2us(acc[2]+b0v+pp[qb2*128+c0]); s1.y=f2us(acc[3]+b1v+pp[qb2*128+c0+1]);
            *(ushort2*)(Oo+(size_t)(r0+ra)*128+c0)=s0;
            *(ushort2*)(Oo+(size_t)(r0+rb)*128+c0)=s1;
        }
    } else if(bid<880){
        // transpose+convert: wsWT[m][c*128+k] = W[m][k*128+c]
        int j=bid-768; int m=j>>4; int idx=(j&15)*256+tid;   // float4 idx
        const float* base;
        switch(m){
            case 0: base=a.W1; break;        case 1: base=a.W2; break;
            case 2: base=a.Wq+16384; break;  case 3: base=a.Wk+16384; break;
            case 4: base=a.Wv+16384; break;  case 5: base=a.W1+16384; break;
            default: base=a.W2+16384; break;
        }
        float4 v=((const float4*)base)[idx];
        int kRow = idx>>5;            // source row
        int c0 = (idx&31)*4;          // source col base
        us16* dst = a.wsWT + (size_t)m*16384;
        dst[(size_t)(c0+0)*128 + kRow]=f2us(v.x);
        dst[(size_t)(c0+1)*128 + kRow]=f2us(v.y);
        dst[(size_t)(c0+2)*128 + kRow]=f2us(v.z);
        dst[(size_t)(c0+3)*128 + kRow]=f2us(v.w);
    } else {
        int gi=(bid-880)*256+tid;     // 2 x 8224 float4
        if(gi<8224){
            float4 v=((const float4*)a.timeK)[gi];
            ushort4 o; o.x=f2us(v.x);o.y=f2us(v.y);o.z=f2us(v.z);o.w=f2us(v.w);
            ((ushort4*)a.tmK)[gi]=o;
        } else if(gi<16448){
            int g2=gi-8224;
            float4 v=((const float4*)a.timeV)[g2];
            ushort4 o; o.x=f2us(v.x);o.y=f2us(v.y);o.z=f2us(v.z);o.w=f2us(v.w);
            ((ushort4*)a.tmV)[g2]=o;
        }
    }
}

// k_blk: one block per (b, q-pair {p,255-p}).
// DQT precompute -> scores -> softmax -> PV -> LN2 -> FFN -> mask,
// then (layer0) LN1+QKV(L1) via W^T gemvs, (layer1) LNf+logits.
__global__ __launch_bounds__(256,5) void k_blk(KArgs a, int layer){
    __shared__ __align__(16) char smem[32768];
    float* sQ  =(float*)smem;            // [2][128]
    float* sS  =(float*)(smem+1024);     // [2][4][256]
    int*   sTM =(int*)  (smem+9216);     // [2][256]
    float* sPr =(float*)(smem+11264);    // [2][8][128]
    float* sDQ =(float*)(smem+19456);    // [2][4][257]
    float* sRed=(float*)(smem+27680);    // 4
    float* sRed2=(float*)(smem+27696);   // 4
    float* sX  =(float*)(smem+28672);    // [2][128]
    float* sH  =(float*)(smem+29696);    // [2][128]
    float* sY  =(float*)(smem+30720);    // [2][128]
    float* sRB =(float*)(smem+31744);    // 8

    int tid=threadIdx.x, bid=blockIdx.x;
    int b=bid>>7, p=bid&127;
    int q1=p, q2=255-p, b0=b*L_;
    int r1=b0+q1, r2=b0+q2;
    bool pad1=a.log_seqs[r1]==0, pad2=a.log_seqs[r2]==0;
    const us16* Qb = layer? a.Qb1:a.Qb0;
    const us16* Kb = layer? a.Kb1:a.Kb0;
    const us16* Vb = layer? a.Vb1:a.Vb0;
    const float* qin = layer? a.qin1:a.qin0;
    const float scale=0.17677669529663687f;   // 1/sqrt(32)
    if(tid<128) sQ[tid]=us2f(Qb[(size_t)r1*128+tid])*scale;
    else        sQ[tid]=us2f(Qb[(size_t)r2*128+(tid-128)])*scale;
    int k=tid;
    int tm1=a.tmat[(size_t)r1*L_+k], tm2=a.tmat[(size_t)r2*L_+k];
    sTM[k]=tm1; sTM[256+k]=tm2;
    __syncthreads();

    // phase 0: DQT[i2][h][t] = Qs_h . timeK_h[t]  (coalesced scan of tmK table)
    for(int j=tid;j<514;j+=256){
        int i2 = j>=257; int t = j - i2*257;
        const uint4* T4=(const uint4*)(a.tmK+(size_t)t*128);
        const float* Qs = sQ + i2*128;
        float acc[4]={0.f,0.f,0.f,0.f};
        #pragma unroll
        for(int c=0;c<16;c++){
            uint4 tv=T4[c];
            const us16* tu=(const us16*)&tv;
            const float* qq=Qs+c*8;
            acc[c>>2] += qq[0]*us2f(tu[0])+qq[1]*us2f(tu[1])
                       + qq[2]*us2f(tu[2])+qq[3]*us2f(tu[3])
                       + qq[4]*us2f(tu[4])+qq[5]*us2f(tu[5])
                       + qq[6]*us2f(tu[6])+qq[7]*us2f(tu[7]);
        }
        #pragma unroll
        for(int h=0;h<H_;h++) sDQ[(i2*4+h)*257+t]=acc[h];
    }
    __syncthreads();

    // phase 1: scores = Qs.K' + DQT[h][tm]; K chunk converted once, both queries
    {
        const uint4* K4=(const uint4*)(Kb+(size_t)(b0+k)*128);
        float accA[4]={0.f,0.f,0.f,0.f}, accB[4]={0.f,0.f,0.f,0.f};
        #pragma unroll
        for(int c=0;c<16;c++){
            uint4 kv=K4[c];
            const us16* ku=(const us16*)&kv;
            float kf0=us2f(ku[0]),kf1=us2f(ku[1]),kf2=us2f(ku[2]),kf3=us2f(ku[3]);
            float kf4=us2f(ku[4]),kf5=us2f(ku[5]),kf6=us2f(ku[6]),kf7=us2f(ku[7]);
            const float* qa=sQ+c*8;
            const float* qb=sQ+128+c*8;
            accA[c>>2] += qa[0]*kf0+qa[1]*kf1+qa[2]*kf2+qa[3]*kf3
                        + qa[4]*kf4+qa[5]*kf5+qa[6]*kf6+qa[7]*kf7;
            accB[c>>2] += qb[0]*kf0+qb[1]*kf1+qb[2]*kf2+qb[3]*kf3
                        + qb[4]*kf4+qb[5]*kf5+qb[6]*kf6+qb[7]*kf7;
        }
        bool act1=(k<=q1)&&!pad1, act2=(k<=q2)&&!pad2;
        #pragma unroll
        for(int h=0;h<H_;h++){
            sS[h*256+k]     = act1? accA[h]+sDQ[h*257+tm1]     : NEGV;
            sS[(4+h)*256+k] = act2? accB[h]+sDQ[(4+h)*257+tm2] : NEGV;
        }
    }
    __syncthreads();

    // phase 2: softmax; wave h -> head h, both queries
    {
        int h=tid>>6, lane=tid&63;
        #pragma unroll
        for(int i2=0;i2<2;i2++){
            float* row=sS+(i2*4+h)*256;
            float v0=row[lane],v1=row[lane+64],v2=row[lane+128],v3=row[lane+192];
            float mm=fmaxf(fmaxf(v0,v1),fmaxf(v2,v3));
            #pragma unroll
            for(int o=32;o;o>>=1) mm=fmaxf(mm,__shfl_xor(mm,o,64));
            float e0=__expf(v0-mm),e1=__expf(v1-mm),e2=__expf(v2-mm),e3=__expf(v3-mm);
            float ss=e0+e1+e2+e3;
            #pragma unroll
            for(int o=32;o;o>>=1) ss+=__shfl_xor(ss,o,64);
            float inv=1.f/ss;
            row[lane]=e0*inv; row[lane+64]=e1*inv; row[lane+128]=e2*inv; row[lane+192]=e3*inv;
        }
    }
    __syncthreads();

    // phase 3: A @ (V'+timeV[tm]); queries split across thread halves, 16B loads
    {
        int i2=tid>>7, s8=(tid>>4)&7, dq=tid&15;    // 8 dims/thread, head=dq>>2
        int qq=i2?q2:q1; bool pad=i2?pad2:pad1;
        int kend=pad?L_:qq+1;
        int k0=s8*32;
        int kmax=kend-k0; kmax=kmax<0?0:(kmax>32?32:kmax);
        const float* row=sS+(i2*4+(dq>>2))*256;
        const int* tmrow=sTM+i2*256;
        float a0=0,a1=0,a2=0,a3=0,a4=0,a5=0,a6=0,a7=0;
        for(int kk=0;kk<kmax;kk++){
            int kx=k0+kk;
            float aa=row[kx];
            int tmk=tmrow[kx];
            uint4 v4=((const uint4*)(Vb+(size_t)(b0+kx)*128))[dq];
            uint4 t4=((const uint4*)(a.tmV+(size_t)tmk*128))[dq];
            const us16* vu=(const us16*)&v4;
            const us16* tu=(const us16*)&t4;
            a0=fmaf(aa,us2f(vu[0])+us2f(tu[0]),a0);
            a1=fmaf(aa,us2f(vu[1])+us2f(tu[1]),a1);
            a2=fmaf(aa,us2f(vu[2])+us2f(tu[2]),a2);
            a3=fmaf(aa,us2f(vu[3])+us2f(tu[3]),a3);
            a4=fmaf(aa,us2f(vu[4])+us2f(tu[4]),a4);
            a5=fmaf(aa,us2f(vu[5])+us2f(tu[5]),a5);
            a6=fmaf(aa,us2f(vu[6])+us2f(tu[6]),a6);
            a7=fmaf(aa,us2f(vu[7])+us2f(tu[7]),a7);
        }
        float* dst=sPr+(i2*8+s8)*128+dq*8;
        ((float4*)dst)[0]=make_float4(a0,a1,a2,a3);
        ((float4*)dst)[1]=make_float4(a4,a5,a6,a7);
    }
    __syncthreads();

    // epilogue: +qin residual, LN2 -> sX
    int ii=tid>>7, l=tid&127;
    bool padown = ii? pad2:pad1;
    int rr = ii? r2:r1;
    int qown = ii? q2:q1;
    {
        float v=qin[(size_t)rr*128+l];
        #pragma unroll
        for(int sl=0;sl<8;sl++) v+=sPr[(ii*8+sl)*128+l];
        float s=v;
        #pragma unroll
        for(int o=32;o;o>>=1) s+=__shfl_xor(s,o,64);
        if((tid&63)==0) sRed[ii*2+((tid>>6)&1)]=s;
        __syncthreads();
        float m=(sRed[ii*2]+sRed[ii*2+1])*(1.f/128.f);
        float d=v-m;
        float vv=d*d;
        #pragma unroll
        for(int o=32;o;o>>=1) vv+=__shfl_xor(vv,o,64);
        if((tid&63)==0) sRed2[ii*2+((tid>>6)&1)]=vv;
        __syncthreads();
        float rstd=rsqrtf((sRed2[ii*2]+sRed2[ii*2+1])*(1.f/128.f)+1e-8f);
        sX[ii*128+l]=d*rstd*a.ln2g[layer*128+l]+a.ln2b[layer*128+l];
    }
    __syncthreads();

    // FFN via W^T direct-from-global gemvs (no LDS staging, no extra barriers)
    int cc=l;
    const us16* WT1 = a.wsWT + (size_t)(layer?5:0)*16384;
    const us16* WT2 = a.wsWT + (size_t)(layer?6:1)*16384;
    {
        float h = gemv_wt(WT1 + (size_t)cc*128, sX+ii*128);
        h = fmaxf(h + a.b1[layer*128+cc], 0.f);
        sH[ii*128+cc]=h;
    }
    __syncthreads();
    float f;
    {
        f = gemv_wt(WT2 + (size_t)cc*128, sH+ii*128)
          + a.b2[layer*128+cc] + sX[ii*128+cc];
        if(padown) f=0.f;
    }

    if(layer==0){
        // LN1(L1) on f -> sX (Q input); raw f -> sY (K,V input)
        sY[ii*128+cc]=f;
        float s=f;
        #pragma unroll
        for(int o=32;o;o>>=1) s+=__shfl_xor(s,o,64);
        if((tid&63)==0) sRB[ii*2+((tid>>6)&1)]=s;
        __syncthreads();
        float m=(sRB[ii*2]+sRB[ii*2+1])*(1.f/128.f);
        float d=f-m;
        float vv=d*d;
        #pragma unroll
        for(int o=32;o;o>>=1) vv+=__shfl_xor(vv,o,64);
        if((tid&63)==0) sRB[4+ii*2+((tid>>6)&1)]=vv;
        __syncthreads();
        float rstd=rsqrtf((sRB[4+ii*2]+sRB[5+ii*2])*(1.f/128.f)+1e-8f);
        float y1=d*rstd*a.ln1g[128+cc]+a.ln1b[128+cc];
        a.qin1[(size_t)rr*128+cc]=y1;
        sX[ii*128+cc]=y1;
        __syncthreads();
        // Q/K/V (L1) — read-only LDS from here, no barriers between gemvs
        {
            float acc = gemv_wt(a.wsWT + (size_t)2*16384 + (size_t)cc*128, sX+ii*128);
            a.Qb1[(size_t)rr*128+cc]=f2us(acc + a.bq[128+cc]);
        }
        {
            float acc = gemv_wt(a.wsWT + (size_t)3*16384 + (size_t)cc*128, sY+ii*128);
            a.Kb1[(size_t)rr*128+cc]=f2us(acc + a.bk[128+cc] + a.posK[qown*128+cc]);
        }
        {
            float acc = gemv_wt(a.wsWT + (size_t)4*16384 + (size_t)cc*128, sY+ii*128);
            a.Vb1[(size_t)rr*128+cc]=f2us(acc + a.bv[128+cc] + a.posV[qown*128+cc]);
        }
    } else {
        // LNf + logits
        float s=f;
        #pragma unroll
        for(int o=32;o;o>>=1) s+=__shfl_xor(s,o,64);
        if((tid&63)==0) sRB[ii*2+((tid>>6)&1)]=s;
        __syncthreads();
        float m=(sRB[ii*2]+sRB[ii*2+1])*(1.f/128.f);
        float d=f-m;
        float vv=d*d;
        #pragma unroll
        for(int o=32;o;o>>=1) vv+=__shfl_xor(vv,o,64);
        if((tid&63)==0) sRB[4+ii*2+((tid>>6)&1)]=vv;
        __syncthreads();
        float rstd=rsqrtf((sRB[4+ii*2]+sRB[5+ii*2])*(1.f/128.f)+1e-8f);
        sX[ii*128+cc]=d*rstd*a.lnfg[cc]+a.lnfb[cc];
        __syncthreads();
        int w=tid>>6, lane=tid&63;
        int rowi=w>>1, neg=w&1;
        int rg = rowi? r2:r1;
        int id = neg? a.neg_seqs[rg] : a.pos_seqs[rg];
        const float* e=a.item_emb+(size_t)id*128;
        float s2 = sX[rowi*128+lane]*e[lane] + sX[rowi*128+lane+64]*e[lane+64];
        #pragma unroll
        for(int o=32;o;o>>=1) s2+=__shfl_xor(s2,o,64);
        if(lane==0) a.out[neg*ROWS+rg]=s2;
    }
}

extern "C" void kernel_launch(void* const* d_in, const int* in_sizes, int n_in,
                              void* d_out, int out_size, void* d_ws, size_t ws_size,
                              hipStream_t stream) {
    KArgs a;
    a.log_seqs=(const int*)d_in[1];
    a.tmat    =(const int*)d_in[2];
    a.pos_seqs=(const int*)d_in[3];
    a.neg_seqs=(const int*)d_in[4];
    a.item_emb=(const float*)d_in[5];
    a.posK =(const float*)d_in[6];
    a.posV =(const float*)d_in[7];
    a.timeK=(const float*)d_in[8];
    a.timeV=(const float*)d_in[9];
    a.ln1g=(const float*)d_in[10];
    a.ln1b=(const float*)d_in[11];
    a.Wq=(const float*)d_in[12];
    a.bq=(const float*)d_in[13];
    a.Wk=(const float*)d_in[14];
    a.bk=(const float*)d_in[15];
    a.Wv=(const float*)d_in[16];
    a.bv=(const float*)d_in[17];
    a.ln2g=(const float*)d_in[18];
    a.ln2b=(const float*)d_in[19];
    a.W1=(const float*)d_in[20];
    a.b1=(const float*)d_in[21];
    a.W2=(const float*)d_in[22];
    a.b2=(const float*)d_in[23];
    a.lnfg=(const float*)d_in[24];
    a.lnfb=(const float*)d_in[25];

    const size_t MB=1u<<20;
    char* w=(char*)d_ws;
    a.qin0=(float*)(w+0*MB);
    a.qin1=(float*)(w+1*MB);
    a.Qb0 =(us16*) (w+2*MB);
    a.Kb0 =(us16*) (w+2*MB+512*1024);
    a.Vb0 =(us16*) (w+3*MB);
    a.Qb1 =(us16*) (w+3*MB+512*1024);
    a.Kb1 =(us16*) (w+4*MB);
    a.Vb1 =(us16*) (w+4*MB+512*1024);
    a.wsWT=(us16*) (w+5*MB);              // 7 x 32KB, transposed
    a.tmK =(us16*) (w+5*MB+256*1024);     // 65792 B
    a.tmV =(us16*) (w+5*MB+384*1024);
    a.out =(float*)d_out;

    k_pre<<<946,256,0,stream>>>(a);
    k_blk<<<1024,256,0,stream>>>(a,0);
    k_blk<<<1024,256,0,stream>>>(a,1);
}

// Round 11
// 243.657 us; speedup vs baseline: 1.6661x; 1.6661x over previous
//
#include <hip/hip_runtime.h>
#include <hip/hip_bf16.h>

#define L_ 256
#define H_ 4
#define ROWS 2048
#define NEGV (-4294967295.0f)   // -(2^32)+1 as float

typedef unsigned short us16;

__device__ __forceinline__ float us2f(us16 u){ return __uint_as_float(((unsigned)u)<<16); }
__device__ __forceinline__ us16 f2us(float f){ __hip_bfloat16 h=__float2bfloat16(f); return *(us16*)&h; }

struct KArgs {
    const int *log_seqs, *tmat, *pos_seqs, *neg_seqs;
    const float *item_emb, *posK, *posV, *timeK, *timeV;
    const float *ln1g, *ln1b, *bq, *bk, *bv, *ln2g, *ln2b, *b1, *b2, *lnfg, *lnfb;
    const float *Wq, *Wk, *Wv, *W1, *W2;
    float *qin0, *qin1, *out;
    us16 *wsWT, *tmK, *tmV, *Qb0, *Kb0, *Vb0, *Qb1, *Kb1, *Vb1;
};

// LayerNorm of 8 LDS rows in place; thread t: row t>>5, 4 elems strided 32.
__device__ __forceinline__ void ln_rows(float* sA,
        const float* __restrict__ g, const float* __restrict__ b,
        float* qin_out, int r0, int tid){
    int r=tid>>5, l=tid&31;
    float* x=sA+r*128;
    float x0=x[l],x1=x[l+32],x2=x[l+64],x3=x[l+96];
    float s=x0+x1+x2+x3;
    #pragma unroll
    for(int o=16;o;o>>=1) s+=__shfl_xor(s,o,64);
    float m=s*(1.f/128.f);
    float d0=x0-m,d1=x1-m,d2=x2-m,d3=x3-m;
    float v=d0*d0+d1*d1+d2*d2+d3*d3;
    #pragma unroll
    for(int o=16;o;o>>=1) v+=__shfl_xor(v,o,64);
    float rstd=rsqrtf(v*(1.f/128.f)+1e-8f);
    float y0=d0*rstd*g[l]+b[l];
    float y1=d1*rstd*g[l+32]+b[l+32];
    float y2=d2*rstd*g[l+64]+b[l+64];
    float y3=d3*rstd*g[l+96]+b[l+96];
    x[l]=y0; x[l+32]=y1; x[l+64]=y2; x[l+96]=y3;
    if(qin_out){
        float* q=qin_out+(size_t)(r0+r)*128;
        q[l]=y0; q[l+32]=y1; q[l+64]=y2; q[l+96]=y3;
    }
}

// 2-row x 2-col register tile over K=128 from LDS
__device__ __forceinline__ void gemm2x2(const float* A, const us16* sW,
        int ra, int rb, int c0, float* acc){
    float a00=0,a01=0,a10=0,a11=0;
    const float* Ar=A+ra*128;
    const float* Br=A+rb*128;
    #pragma unroll 8
    for(int k=0;k<128;k++){
        ushort2 wp=*(const ushort2*)(sW+k*128+c0);
        float w0=us2f(wp.x), w1=us2f(wp.y);
        float x0=Ar[k], x1=Br[k];
        a00=fmaf(x0,w0,a00); a01=fmaf(x0,w1,a01);
        a10=fmaf(x1,w0,a10); a11=fmaf(x1,w1,a11);
    }
    acc[0]=a00; acc[1]=a01; acc[2]=a10; acc[3]=a11;
}

// dot of bf16 row (global, contiguous 128) with fp32 LDS row (wave-broadcast).
// unroll 4 -> at most 4 uint4 loads in flight (~16 VGPRs), avoids spill (R10 lesson).
__device__ __forceinline__ float gemv_wt(const us16* __restrict__ wt, const float* x){
    float acc=0;
    const uint4* W4=(const uint4*)wt;
    #pragma unroll 4
    for(int c=0;c<16;c++){
        uint4 wv=W4[c];
        const us16* wu=(const us16*)&wv;
        const float* xx=x+c*8;
        acc += xx[0]*us2f(wu[0])+xx[1]*us2f(wu[1])+xx[2]*us2f(wu[2])+xx[3]*us2f(wu[3])
             + xx[4]*us2f(wu[4])+xx[5]*us2f(wu[5])+xx[6]*us2f(wu[6])+xx[7]*us2f(wu[7]);
    }
    return acc;
}

// k_pre: bid<768: embed+LN1+QKV(L0) (8 rows/block, fp32 weights staged->bf16 LDS).
//        bid 768..879: convert+TRANSPOSE 7 tail matrices fp32 -> bf16 wsWT.
//        bid 880..945: convert timeK/timeV tables to bf16.
__global__ __launch_bounds__(256) void k_pre(KArgs a){
    __shared__ __align__(16) char smem[36864];
    int tid=threadIdx.x, bid=blockIdx.x;
    if(bid<768){
        us16* sW=(us16*)smem;
        float* sA=(float*)(smem+32768);
        int m=bid>>8, rg=bid&255, r0=rg*8;
        {   // embed 8 rows
            int rl=tid>>5, c4=tid&31;
            int id=a.log_seqs[r0+rl];
            float4 v=((const float4*)a.item_emb)[id*32+c4];
            float sc = id? 11.3137085f : 0.f;   // sqrt(128), pad-zeroed
            v.x*=sc; v.y*=sc; v.z*=sc; v.w*=sc;
            ((float4*)sA)[tid]=v;
        }
        const float* Wsrc=(m==0)?a.Wq:(m==1)?a.Wk:a.Wv;
        {   // stage fp32 weights -> bf16 LDS
            const float4* src=(const float4*)Wsrc;
            ushort4* dst=(ushort4*)sW;
            #pragma unroll
            for(int j=0;j<16;j++){
                float4 w=src[j*256+tid];
                ushort4 o; o.x=f2us(w.x);o.y=f2us(w.y);o.z=f2us(w.z);o.w=f2us(w.w);
                dst[j*256+tid]=o;
            }
        }
        __syncthreads();
        if(m==0){ ln_rows(sA, a.ln1g, a.ln1b, a.qin0, r0, tid); __syncthreads(); }
        int cp=tid&63, rp=tid>>6, c0=2*cp, ra=2*rp, rb=ra+1;
        float acc[4];
        gemm2x2(sA,sW,ra,rb,c0,acc);
        if(m==0){
            float b0v=a.bq[c0], b1v=a.bq[c0+1];
            ushort2 s0; s0.x=f2us(acc[0]+b0v); s0.y=f2us(acc[1]+b1v);
            ushort2 s1; s1.x=f2us(acc[2]+b0v); s1.y=f2us(acc[3]+b1v);
            *(ushort2*)(a.Qb0+(size_t)(r0+ra)*128+c0)=s0;
            *(ushort2*)(a.Qb0+(size_t)(r0+rb)*128+c0)=s1;
        } else {
            const float* bb=(m==1)?a.bk:a.bv;
            const float* pp=(m==1)?a.posK:a.posV;
            us16* Oo=(m==1)?a.Kb0:a.Vb0;
            int qa=(r0+ra)&255, qb2=(r0+rb)&255;
            float b0v=bb[c0], b1v=bb[c0+1];
            ushort2 s0; s0.x=f2us(acc[0]+b0v+pp[qa*128+c0]);  s0.y=f2us(acc[1]+b1v+pp[qa*128+c0+1]);
            ushort2 s1; s1.x=f2us(acc[2]+b0v+pp[qb2*128+c0]); s1.y=f2us(acc[3]+b1v+pp[qb2*128+c0+1]);
            *(ushort2*)(Oo+(size_t)(r0+ra)*128+c0)=s0;
            *(ushort2*)(Oo+(size_t)(r0+rb)*128+c0)=s1;
        }
    } else if(bid<880){
        // transpose+convert: wsWT[m][c*128+k] = W[m][k*128+c]
        int j=bid-768; int m=j>>4; int idx=(j&15)*256+tid;   // float4 idx
        const float* base;
        switch(m){
            case 0: base=a.W1; break;        case 1: base=a.W2; break;
            case 2: base=a.Wq+16384; break;  case 3: base=a.Wk+16384; break;
            case 4: base=a.Wv+16384; break;  case 5: base=a.W1+16384; break;
            default: base=a.W2+16384; break;
        }
        float4 v=((const float4*)base)[idx];
        int kRow = idx>>5;            // source row
        int c0 = (idx&31)*4;          // source col base
        us16* dst = a.wsWT + (size_t)m*16384;
        dst[(size_t)(c0+0)*128 + kRow]=f2us(v.x);
        dst[(size_t)(c0+1)*128 + kRow]=f2us(v.y);
        dst[(size_t)(c0+2)*128 + kRow]=f2us(v.z);
        dst[(size_t)(c0+3)*128 + kRow]=f2us(v.w);
    } else {
        int gi=(bid-880)*256+tid;     // 2 x 8224 float4
        if(gi<8224){
            float4 v=((const float4*)a.timeK)[gi];
            ushort4 o; o.x=f2us(v.x);o.y=f2us(v.y);o.z=f2us(v.z);o.w=f2us(v.w);
            ((ushort4*)a.tmK)[gi]=o;
        } else if(gi<16448){
            int g2=gi-8224;
            float4 v=((const float4*)a.timeV)[g2];
            ushort4 o; o.x=f2us(v.x);o.y=f2us(v.y);o.z=f2us(v.z);o.w=f2us(v.w);
            ((ushort4*)a.tmV)[g2]=o;
        }
    }
}

// k_blk: one block per (b, q-pair {p,255-p}).
// DQT precompute -> scores -> softmax -> PV -> LN2 -> FFN -> mask,
// then (layer0) LN1+QKV(L1) via W^T gemvs, (layer1) LNf+logits.
__global__ __launch_bounds__(256,4) void k_blk(KArgs a, int layer){
    __shared__ __align__(16) char smem[32768];
    float* sQ  =(float*)smem;            // [2][128]
    float* sS  =(float*)(smem+1024);     // [2][4][256]
    int*   sTM =(int*)  (smem+9216);     // [2][256]
    float* sPr =(float*)(smem+11264);    // [2][8][128]
    float* sDQ =(float*)(smem+19456);    // [2][4][257]
    float* sRed=(float*)(smem+27680);    // 4
    float* sRed2=(float*)(smem+27696);   // 4
    float* sX  =(float*)(smem+28672);    // [2][128]
    float* sH  =(float*)(smem+29696);    // [2][128]
    float* sY  =(float*)(smem+30720);    // [2][128]
    float* sRB =(float*)(smem+31744);    // 8

    int tid=threadIdx.x, bid=blockIdx.x;
    int b=bid>>7, p=bid&127;
    int q1=p, q2=255-p, b0=b*L_;
    int r1=b0+q1, r2=b0+q2;
    bool pad1=a.log_seqs[r1]==0, pad2=a.log_seqs[r2]==0;
    const us16* Qb = layer? a.Qb1:a.Qb0;
    const us16* Kb = layer? a.Kb1:a.Kb0;
    const us16* Vb = layer? a.Vb1:a.Vb0;
    const float* qin = layer? a.qin1:a.qin0;
    const float scale=0.17677669529663687f;   // 1/sqrt(32)
    if(tid<128) sQ[tid]=us2f(Qb[(size_t)r1*128+tid])*scale;
    else        sQ[tid]=us2f(Qb[(size_t)r2*128+(tid-128)])*scale;
    int k=tid;
    int tm1=a.tmat[(size_t)r1*L_+k], tm2=a.tmat[(size_t)r2*L_+k];
    sTM[k]=tm1; sTM[256+k]=tm2;
    __syncthreads();

    // phase 0: DQT[i2][h][t] = Qs_h . timeK_h[t]  (coalesced scan of tmK table)
    for(int j=tid;j<514;j+=256){
        int i2 = j>=257; int t = j - i2*257;
        const uint4* T4=(const uint4*)(a.tmK+(size_t)t*128);
        const float* Qs = sQ + i2*128;
        float acc[4]={0.f,0.f,0.f,0.f};
        #pragma unroll 4
        for(int c=0;c<16;c++){
            uint4 tv=T4[c];
            const us16* tu=(const us16*)&tv;
            const float* qq=Qs+c*8;
            acc[c>>2] += qq[0]*us2f(tu[0])+qq[1]*us2f(tu[1])
                       + qq[2]*us2f(tu[2])+qq[3]*us2f(tu[3])
                       + qq[4]*us2f(tu[4])+qq[5]*us2f(tu[5])
                       + qq[6]*us2f(tu[6])+qq[7]*us2f(tu[7]);
        }
        #pragma unroll
        for(int h=0;h<H_;h++) sDQ[(i2*4+h)*257+t]=acc[h];
    }
    __syncthreads();

    // phase 1: scores = Qs.K' + DQT[h][tm]; K chunk converted once, both queries
    {
        const uint4* K4=(const uint4*)(Kb+(size_t)(b0+k)*128);
        float accA[4]={0.f,0.f,0.f,0.f}, accB[4]={0.f,0.f,0.f,0.f};
        #pragma unroll 4
        for(int c=0;c<16;c++){
            uint4 kv=K4[c];
            const us16* ku=(const us16*)&kv;
            float kf0=us2f(ku[0]),kf1=us2f(ku[1]),kf2=us2f(ku[2]),kf3=us2f(ku[3]);
            float kf4=us2f(ku[4]),kf5=us2f(ku[5]),kf6=us2f(ku[6]),kf7=us2f(ku[7]);
            const float* qa=sQ+c*8;
            const float* qb=sQ+128+c*8;
            accA[c>>2] += qa[0]*kf0+qa[1]*kf1+qa[2]*kf2+qa[3]*kf3
                        + qa[4]*kf4+qa[5]*kf5+qa[6]*kf6+qa[7]*kf7;
            accB[c>>2] += qb[0]*kf0+qb[1]*kf1+qb[2]*kf2+qb[3]*kf3
                        + qb[4]*kf4+qb[5]*kf5+qb[6]*kf6+qb[7]*kf7;
        }
        bool act1=(k<=q1)&&!pad1, act2=(k<=q2)&&!pad2;
        #pragma unroll
        for(int h=0;h<H_;h++){
            sS[h*256+k]     = act1? accA[h]+sDQ[h*257+tm1]     : NEGV;
            sS[(4+h)*256+k] = act2? accB[h]+sDQ[(4+h)*257+tm2] : NEGV;
        }
    }
    __syncthreads();

    // phase 2: softmax; wave h -> head h, both queries
    {
        int h=tid>>6, lane=tid&63;
        #pragma unroll
        for(int i2=0;i2<2;i2++){
            float* row=sS+(i2*4+h)*256;
            float v0=row[lane],v1=row[lane+64],v2=row[lane+128],v3=row[lane+192];
            float mm=fmaxf(fmaxf(v0,v1),fmaxf(v2,v3));
            #pragma unroll
            for(int o=32;o;o>>=1) mm=fmaxf(mm,__shfl_xor(mm,o,64));
            float e0=__expf(v0-mm),e1=__expf(v1-mm),e2=__expf(v2-mm),e3=__expf(v3-mm);
            float ss=e0+e1+e2+e3;
            #pragma unroll
            for(int o=32;o;o>>=1) ss+=__shfl_xor(ss,o,64);
            float inv=1.f/ss;
            row[lane]=e0*inv; row[lane+64]=e1*inv; row[lane+128]=e2*inv; row[lane+192]=e3*inv;
        }
    }
    __syncthreads();

    // phase 3: A @ (V'+timeV[tm]); queries split across thread halves, 16B loads
    {
        int i2=tid>>7, s8=(tid>>4)&7, dq=tid&15;    // 8 dims/thread, head=dq>>2
        int qq=i2?q2:q1; bool pad=i2?pad2:pad1;
        int kend=pad?L_:qq+1;
        int k0=s8*32;
        int kmax=kend-k0; kmax=kmax<0?0:(kmax>32?32:kmax);
        const float* row=sS+(i2*4+(dq>>2))*256;
        const int* tmrow=sTM+i2*256;
        float a0=0,a1=0,a2=0,a3=0,a4=0,a5=0,a6=0,a7=0;
        for(int kk=0;kk<kmax;kk++){
            int kx=k0+kk;
            float aa=row[kx];
            int tmk=tmrow[kx];
            uint4 v4=((const uint4*)(Vb+(size_t)(b0+kx)*128))[dq];
            uint4 t4=((const uint4*)(a.tmV+(size_t)tmk*128))[dq];
            const us16* vu=(const us16*)&v4;
            const us16* tu=(const us16*)&t4;
            a0=fmaf(aa,us2f(vu[0])+us2f(tu[0]),a0);
            a1=fmaf(aa,us2f(vu[1])+us2f(tu[1]),a1);
            a2=fmaf(aa,us2f(vu[2])+us2f(tu[2]),a2);
            a3=fmaf(aa,us2f(vu[3])+us2f(tu[3]),a3);
            a4=fmaf(aa,us2f(vu[4])+us2f(tu[4]),a4);
            a5=fmaf(aa,us2f(vu[5])+us2f(tu[5]),a5);
            a6=fmaf(aa,us2f(vu[6])+us2f(tu[6]),a6);
            a7=fmaf(aa,us2f(vu[7])+us2f(tu[7]),a7);
        }
        float* dst=sPr+(i2*8+s8)*128+dq*8;
        ((float4*)dst)[0]=make_float4(a0,a1,a2,a3);
        ((float4*)dst)[1]=make_float4(a4,a5,a6,a7);
    }
    __syncthreads();

    // epilogue: +qin residual, LN2 -> sX
    int ii=tid>>7, l=tid&127;
    bool padown = ii? pad2:pad1;
    int rr = ii? r2:r1;
    int qown = ii? q2:q1;
    {
        float v=qin[(size_t)rr*128+l];
        #pragma unroll
        for(int sl=0;sl<8;sl++) v+=sPr[(ii*8+sl)*128+l];
        float s=v;
        #pragma unroll
        for(int o=32;o;o>>=1) s+=__shfl_xor(s,o,64);
        if((tid&63)==0) sRed[ii*2+((tid>>6)&1)]=s;
        __syncthreads();
        float m=(sRed[ii*2]+sRed[ii*2+1])*(1.f/128.f);
        float d=v-m;
        float vv=d*d;
        #pragma unroll
        for(int o=32;o;o>>=1) vv+=__shfl_xor(vv,o,64);
        if((tid&63)==0) sRed2[ii*2+((tid>>6)&1)]=vv;
        __syncthreads();
        float rstd=rsqrtf((sRed2[ii*2]+sRed2[ii*2+1])*(1.f/128.f)+1e-8f);
        sX[ii*128+l]=d*rstd*a.ln2g[layer*128+l]+a.ln2b[layer*128+l];
    }
    __syncthreads();

    // FFN via W^T direct-from-global gemvs (no LDS staging, no extra barriers)
    int cc=l;
    const us16* WT1 = a.wsWT + (size_t)(layer?5:0)*16384;
    const us16* WT2 = a.wsWT + (size_t)(layer?6:1)*16384;
    {
        float h = gemv_wt(WT1 + (size_t)cc*128, sX+ii*128);
        h = fmaxf(h + a.b1[layer*128+cc], 0.f);
        sH[ii*128+cc]=h;
    }
    __syncthreads();
    float f;
    {
        f = gemv_wt(WT2 + (size_t)cc*128, sH+ii*128)
          + a.b2[layer*128+cc] + sX[ii*128+cc];
        if(padown) f=0.f;
    }

    if(layer==0){
        // LN1(L1) on f -> sX (Q input); raw f -> sY (K,V input)
        sY[ii*128+cc]=f;
        float s=f;
        #pragma unroll
        for(int o=32;o;o>>=1) s+=__shfl_xor(s,o,64);
        if((tid&63)==0) sRB[ii*2+((tid>>6)&1)]=s;
        __syncthreads();
        float m=(sRB[ii*2]+sRB[ii*2+1])*(1.f/128.f);
        float d=f-m;
        float vv=d*d;
        #pragma unroll
        for(int o=32;o;o>>=1) vv+=__shfl_xor(vv,o,64);
        if((tid&63)==0) sRB[4+ii*2+((tid>>6)&1)]=vv;
        __syncthreads();
        float rstd=rsqrtf((sRB[4+ii*2]+sRB[5+ii*2])*(1.f/128.f)+1e-8f);
        float y1=d*rstd*a.ln1g[128+cc]+a.ln1b[128+cc];
        a.qin1[(size_t)rr*128+cc]=y1;
        sX[ii*128+cc]=y1;
        __syncthreads();
        // Q/K/V (L1) — read-only LDS from here, no barriers between gemvs
        {
            float acc = gemv_wt(a.wsWT + (size_t)2*16384 + (size_t)cc*128, sX+ii*128);
            a.Qb1[(size_t)rr*128+cc]=f2us(acc + a.bq[128+cc]);
        }
        {
            float acc = gemv_wt(a.wsWT + (size_t)3*16384 + (size_t)cc*128, sY+ii*128);
            a.Kb1[(size_t)rr*128+cc]=f2us(acc + a.bk[128+cc] + a.posK[qown*128+cc]);
        }
        {
            float acc = gemv_wt(a.wsWT + (size_t)4*16384 + (size_t)cc*128, sY+ii*128);
            a.Vb1[(size_t)rr*128+cc]=f2us(acc + a.bv[128+cc] + a.posV[qown*128+cc]);
        }
    } else {
        // LNf + logits
        float s=f;
        #pragma unroll
        for(int o=32;o;o>>=1) s+=__shfl_xor(s,o,64);
        if((tid&63)==0) sRB[ii*2+((tid>>6)&1)]=s;
        __syncthreads();
        float m=(sRB[ii*2]+sRB[ii*2+1])*(1.f/128.f);
        float d=f-m;
        float vv=d*d;
        #pragma unroll
        for(int o=32;o;o>>=1) vv+=__shfl_xor(vv,o,64);
        if((tid&63)==0) sRB[4+ii*2+((tid>>6)&1)]=vv;
        __syncthreads();
        float rstd=rsqrtf((sRB[4+ii*2]+sRB[5+ii*2])*(1.f/128.f)+1e-8f);
        sX[ii*128+cc]=d*rstd*a.lnfg[cc]+a.lnfb[cc];
        __syncthreads();
        int w=tid>>6, lane=tid&63;
        int rowi=w>>1, neg=w&1;
        int rg = rowi? r2:r1;
        int id = neg? a.neg_seqs[rg] : a.pos_seqs[rg];
        const float* e=a.item_emb+(size_t)id*128;
        float s2 = sX[rowi*128+lane]*e[lane] + sX[rowi*128+lane+64]*e[lane+64];
        #pragma unroll
        for(int o=32;o;o>>=1) s2+=__shfl_xor(s2,o,64);
        if(lane==0) a.out[neg*ROWS+rg]=s2;
    }
}

extern "C" void kernel_launch(void* const* d_in, const int* in_sizes, int n_in,
                              void* d_out, int out_size, void* d_ws, size_t ws_size,
                              hipStream_t stream) {
    KArgs a;
    a.log_seqs=(const int*)d_in[1];
    a.tmat    =(const int*)d_in[2];
    a.pos_seqs=(const int*)d_in[3];
    a.neg_seqs=(const int*)d_in[4];
    a.item_emb=(const float*)d_in[5];
    a.posK =(const float*)d_in[6];
    a.posV =(const float*)d_in[7];
    a.timeK=(const float*)d_in[8];
    a.timeV=(const float*)d_in[9];
    a.ln1g=(const float*)d_in[10];
    a.ln1b=(const float*)d_in[11];
    a.Wq=(const float*)d_in[12];
    a.bq=(const float*)d_in[13];
    a.Wk=(const float*)d_in[14];
    a.bk=(const float*)d_in[15];
    a.Wv=(const float*)d_in[16];
    a.bv=(const float*)d_in[17];
    a.ln2g=(const float*)d_in[18];
    a.ln2b=(const float*)d_in[19];
    a.W1=(const float*)d_in[20];
    a.b1=(const float*)d_in[21];
    a.W2=(const float*)d_in[22];
    a.b2=(const float*)d_in[23];
    a.lnfg=(const float*)d_in[24];
    a.lnfb=(const float*)d_in[25];

    const size_t MB=1u<<20;
    char* w=(char*)d_ws;
    a.qin0=(float*)(w+0*MB);
    a.qin1=(float*)(w+1*MB);
    a.Qb0 =(us16*) (w+2*MB);
    a.Kb0 =(us16*) (w+2*MB+512*1024);
    a.Vb0 =(us16*) (w+3*MB);
    a.Qb1 =(us16*) (w+3*MB+512*1024);
    a.Kb1 =(us16*) (w+4*MB);
    a.Vb1 =(us16*) (w+4*MB+512*1024);
    a.wsWT=(us16*) (w+5*MB);              // 7 x 32KB, transposed
    a.tmK =(us16*) (w+5*MB+256*1024);     // 65792 B
    a.tmV =(us16*) (w+5*MB+384*1024);
    a.out =(float*)d_out;

    k_pre<<<946,256,0,stream>>>(a);
    k_blk<<<1024,256,0,stream>>>(a,0);
    k_blk<<<1024,256,0,stream>>>(a,1);
}

// Round 12
// 231.289 us; speedup vs baseline: 1.7552x; 1.0535x over previous
//
#include <hip/hip_runtime.h>
#include <hip/hip_bf16.h>

#define L_ 256
#define H_ 4
#define ROWS 2048
#define NEGV (-4294967295.0f)   // -(2^32)+1 as float

typedef unsigned short us16;

__device__ __forceinline__ float us2f(us16 u){ return __uint_as_float(((unsigned)u)<<16); }
__device__ __forceinline__ us16 f2us(float f){ __hip_bfloat16 h=__float2bfloat16(f); return *(us16*)&h; }

struct KArgs {
    const int *log_seqs, *tmat, *pos_seqs, *neg_seqs;
    const float *item_emb, *posK, *posV, *timeK, *timeV;
    const float *ln1g, *ln1b, *bq, *bk, *bv, *ln2g, *ln2b, *b1, *b2, *lnfg, *lnfb;
    const float *Wq, *Wk, *Wv, *W1, *W2;
    float *qin0, *qin1, *out;
    us16 *wsW, *tmK, *tmV, *Qb0, *Kb0, *Vb0, *Qb1, *Kb1, *Vb1;
};

// LayerNorm of 8 LDS rows in place; thread t: row t>>5, 4 elems strided 32.
__device__ __forceinline__ void ln_rows(float* sA,
        const float* __restrict__ g, const float* __restrict__ b,
        float* qin_out, int r0, int tid){
    int r=tid>>5, l=tid&31;
    float* x=sA+r*128;
    float x0=x[l],x1=x[l+32],x2=x[l+64],x3=x[l+96];
    float s=x0+x1+x2+x3;
    #pragma unroll
    for(int o=16;o;o>>=1) s+=__shfl_xor(s,o,64);
    float m=s*(1.f/128.f);
    float d0=x0-m,d1=x1-m,d2=x2-m,d3=x3-m;
    float v=d0*d0+d1*d1+d2*d2+d3*d3;
    #pragma unroll
    for(int o=16;o;o>>=1) v+=__shfl_xor(v,o,64);
    float rstd=rsqrtf(v*(1.f/128.f)+1e-8f);
    float y0=d0*rstd*g[l]+b[l];
    float y1=d1*rstd*g[l+32]+b[l+32];
    float y2=d2*rstd*g[l+64]+b[l+64];
    float y3=d3*rstd*g[l+96]+b[l+96];
    x[l]=y0; x[l+32]=y1; x[l+64]=y2; x[l+96]=y3;
    if(qin_out){
        float* q=qin_out+(size_t)(r0+r)*128;
        q[l]=y0; q[l+32]=y1; q[l+64]=y2; q[l+96]=y3;
    }
}

// 2-row x 2-col register tile over K=128 from LDS (k_pre only)
__device__ __forceinline__ void gemm2x2(const float* A, const us16* sW,
        int ra, int rb, int c0, float* acc){
    float a00=0,a01=0,a10=0,a11=0;
    const float* Ar=A+ra*128;
    const float* Br=A+rb*128;
    #pragma unroll 8
    for(int k=0;k<128;k++){
        ushort2 wp=*(const ushort2*)(sW+k*128+c0);
        float w0=us2f(wp.x), w1=us2f(wp.y);
        float x0=Ar[k], x1=Br[k];
        a00=fmaf(x0,w0,a00); a01=fmaf(x0,w1,a01);
        a10=fmaf(x1,w0,a10); a11=fmaf(x1,w1,a11);
    }
    acc[0]=a00; acc[1]=a01; acc[2]=a10; acc[3]=a11;
}

// k_pre: bid<768: embed+LN1+QKV(L0) (8 rows/block, fp32 weights staged->bf16 LDS).
//        bid 768..879: convert 7 tail matrices fp32 -> bf16 wsW (k-major, no transpose).
//        bid 880..945: convert timeK/timeV tables to bf16.
__global__ __launch_bounds__(256) void k_pre(KArgs a){
    __shared__ __align__(16) char smem[36864];
    int tid=threadIdx.x, bid=blockIdx.x;
    if(bid<768){
        us16* sW=(us16*)smem;
        float* sA=(float*)(smem+32768);
        int m=bid>>8, rg=bid&255, r0=rg*8;
        {   // embed 8 rows
            int rl=tid>>5, c4=tid&31;
            int id=a.log_seqs[r0+rl];
            float4 v=((const float4*)a.item_emb)[id*32+c4];
            float sc = id? 11.3137085f : 0.f;   // sqrt(128), pad-zeroed
            v.x*=sc; v.y*=sc; v.z*=sc; v.w*=sc;
            ((float4*)sA)[tid]=v;
        }
        const float* Wsrc=(m==0)?a.Wq:(m==1)?a.Wk:a.Wv;
        {   // stage fp32 weights -> bf16 LDS
            const float4* src=(const float4*)Wsrc;
            ushort4* dst=(ushort4*)sW;
            #pragma unroll
            for(int j=0;j<16;j++){
                float4 w=src[j*256+tid];
                ushort4 o; o.x=f2us(w.x);o.y=f2us(w.y);o.z=f2us(w.z);o.w=f2us(w.w);
                dst[j*256+tid]=o;
            }
        }
        __syncthreads();
        if(m==0){ ln_rows(sA, a.ln1g, a.ln1b, a.qin0, r0, tid); __syncthreads(); }
        int cp=tid&63, rp=tid>>6, c0=2*cp, ra=2*rp, rb=ra+1;
        float acc[4];
        gemm2x2(sA,sW,ra,rb,c0,acc);
        if(m==0){
            float b0v=a.bq[c0], b1v=a.bq[c0+1];
            ushort2 s0; s0.x=f2us(acc[0]+b0v); s0.y=f2us(acc[1]+b1v);
            ushort2 s1; s1.x=f2us(acc[2]+b0v); s1.y=f2us(acc[3]+b1v);
            *(ushort2*)(a.Qb0+(size_t)(r0+ra)*128+c0)=s0;
            *(ushort2*)(a.Qb0+(size_t)(r0+rb)*128+c0)=s1;
        } else {
            const float* bb=(m==1)?a.bk:a.bv;
            const float* pp=(m==1)?a.posK:a.posV;
            us16* Oo=(m==1)?a.Kb0:a.Vb0;
            int qa=(r0+ra)&255, qb2=(r0+rb)&255;
            float b0v=bb[c0], b1v=bb[c0+1];
            ushort2 s0; s0.x=f2us(acc[0]+b0v+pp[qa*128+c0]);  s0.y=f2us(acc[1]+b1v+pp[qa*128+c0+1]);
            ushort2 s1; s1.x=f2us(acc[2]+b0v+pp[qb2*128+c0]); s1.y=f2us(acc[3]+b1v+pp[qb2*128+c0+1]);
            *(ushort2*)(Oo+(size_t)(r0+ra)*128+c0)=s0;
            *(ushort2*)(Oo+(size_t)(r0+rb)*128+c0)=s1;
        }
    } else if(bid<880){
        int j=bid-768; int m=j>>4; int idx=(j&15)*256+tid;   // float4 idx
        const float* base;
        switch(m){
            case 0: base=a.W1; break;        case 1: base=a.W2; break;
            case 2: base=a.Wq+16384; break;  case 3: base=a.Wk+16384; break;
            case 4: base=a.Wv+16384; break;  case 5: base=a.W1+16384; break;
            default: base=a.W2+16384; break;
        }
        float4 v=((const float4*)base)[idx];
        ushort4 o; o.x=f2us(v.x);o.y=f2us(v.y);o.z=f2us(v.z);o.w=f2us(v.w);
        ((ushort4*)(a.wsW+(size_t)m*16384))[idx]=o;
    } else {
        int gi=(bid-880)*256+tid;     // 2 x 8224 float4
        if(gi<8224){
            float4 v=((const float4*)a.timeK)[gi];
            ushort4 o; o.x=f2us(v.x);o.y=f2us(v.y);o.z=f2us(v.z);o.w=f2us(v.w);
            ((ushort4*)a.tmK)[gi]=o;
        } else if(gi<16448){
            int g2=gi-8224;
            float4 v=((const float4*)a.timeV)[g2];
            ushort4 o; o.x=f2us(v.x);o.y=f2us(v.y);o.z=f2us(v.z);o.w=f2us(v.w);
            ((ushort4*)a.tmV)[g2]=o;
        }
    }
}

// stage 128x128 bf16 matrix (32KB) global -> LDS with 512 threads: 4 uint4 each
__device__ __forceinline__ void stage_w512(const us16* __restrict__ Wg, us16* sW, int tid){
    const uint4* src=(const uint4*)Wg;
    uint4* dst=(uint4*)sW;
    #pragma unroll
    for(int j=0;j<4;j++) dst[j*512+tid]=src[j*512+tid];
}

// partial dot: k in [kh*64, kh*64+64), output col cc; x is LDS row (wave-broadcast)
__device__ __forceinline__ float gemv_half(const us16* sW, const float* x, int kh, int cc){
    float acc=0;
    int k0=kh*64;
    #pragma unroll 16
    for(int j=0;j<64;j++)
        acc=fmaf(x[k0+j], us2f(sW[(size_t)(k0+j)*128+cc]), acc);
    return acc;
}

// k_blk: 512 threads, one block per (b, q-pair {p,255-p}).
// attention -> LN2 -> FFN -> mask, then (L0) LN1+QKV(L1), (L1) LNf+logits.
__global__ __launch_bounds__(512,6) void k_blk(KArgs a, int layer){
    __shared__ __align__(16) char smem[38912];
    float* sQ  =(float*)smem;             // [2][128]        0..1024
    float* sS  =(float*)(smem+1024);      // [2][4][256]     1024..9216
    us16*  sTMu=(us16*)(smem+9216);       // [2][256]        9216..10240
    float* sPr =(float*)(smem+10240);     // [2][16][128]    10240..26624
    float* sRed=(float*)(smem+26624);     // 4 floats
    float* sRed2=(float*)(smem+26640);    // 4 floats
    us16*  sW  =(us16*)smem;              // tail 32KB       0..32768 (overlays attn)
    float* sX  =(float*)(smem+32768);     // [2][128]
    float* sH  =(float*)(smem+33792);     // [2][128]
    float* sY  =(float*)(smem+34816);     // [2][128]
    float* sPart=(float*)(smem+35840);    // [512]           35840..37888
    float* sRB =(float*)(smem+37888);     // 8 floats

    int tid=threadIdx.x, bid=blockIdx.x;
    int b=bid>>7, p=bid&127;
    int q1=p, q2=255-p, b0=b*L_;
    int r1=b0+q1, r2=b0+q2;
    bool pad1=a.log_seqs[r1]==0, pad2=a.log_seqs[r2]==0;
    const us16* Qb = layer? a.Qb1:a.Qb0;
    const us16* Kb = layer? a.Kb1:a.Kb0;
    const us16* Vb = layer? a.Vb1:a.Vb0;
    const float* qin = layer? a.qin1:a.qin0;
    const float scale=0.17677669529663687f;   // 1/sqrt(32)
    if(tid<256){
        int i2=tid>>7, l=tid&127;
        sQ[tid]=us2f(Qb[(size_t)(i2?r2:r1)*128+l])*scale;
    }
    int i2g=tid>>8, kg=tid&255;               // (query, key) for phases 0/1
    int rg_ = i2g? r2:r1;
    int tmg = a.tmat[(size_t)rg_*L_+kg];
    sTMu[i2g*256+kg]=(us16)tmg;
    __syncthreads();

    // phase 1: scores = Qs.(K' + timeK[tm]) for own (query, k)
    {
        int qq = i2g? q2:q1; bool pad = i2g? pad2:pad1;
        bool act=(kg<=qq)&&!pad;
        float acc[4]={0.f,0.f,0.f,0.f};
        if(act){
            const uint4* K4=(const uint4*)(Kb+(size_t)(b0+kg)*128);
            const uint4* T4=(const uint4*)(a.tmK+(size_t)tmg*128);
            const float4* Q4=(const float4*)(sQ+i2g*128);
            #pragma unroll 4
            for(int c=0;c<16;c++){
                uint4 kv=K4[c]; uint4 tv=T4[c];
                float4 qa=Q4[2*c], qb=Q4[2*c+1];
                const us16* ku=(const us16*)&kv;
                const us16* tu=(const us16*)&tv;
                acc[c>>2]+= qa.x*(us2f(ku[0])+us2f(tu[0]))
                          + qa.y*(us2f(ku[1])+us2f(tu[1]))
                          + qa.z*(us2f(ku[2])+us2f(tu[2]))
                          + qa.w*(us2f(ku[3])+us2f(tu[3]))
                          + qb.x*(us2f(ku[4])+us2f(tu[4]))
                          + qb.y*(us2f(ku[5])+us2f(tu[5]))
                          + qb.z*(us2f(ku[6])+us2f(tu[6]))
                          + qb.w*(us2f(ku[7])+us2f(tu[7]));
            }
        }
        #pragma unroll
        for(int h=0;h<H_;h++) sS[(i2g*4+h)*256+kg]= act? acc[h]:NEGV;
    }
    __syncthreads();

    // phase 2: softmax; wave w handles row w of 8 (i2 = w>>2, h = w&3)
    {
        int w=tid>>6, lane=tid&63;
        float* row=sS+w*256;
        float v0=row[lane],v1=row[lane+64],v2=row[lane+128],v3=row[lane+192];
        float mm=fmaxf(fmaxf(v0,v1),fmaxf(v2,v3));
        #pragma unroll
        for(int o=32;o;o>>=1) mm=fmaxf(mm,__shfl_xor(mm,o,64));
        float e0=__expf(v0-mm),e1=__expf(v1-mm),e2=__expf(v2-mm),e3=__expf(v3-mm);
        float ss=e0+e1+e2+e3;
        #pragma unroll
        for(int o=32;o;o>>=1) ss+=__shfl_xor(ss,o,64);
        float inv=1.f/ss;
        row[lane]=e0*inv; row[lane+64]=e1*inv; row[lane+128]=e2*inv; row[lane+192]=e3*inv;
    }
    __syncthreads();

    // phase 3: A @ (V'+timeV[tm]); thread = (query, kslice 0..15, dq 0..15)
    {
        int i2=tid>>8, s16=(tid>>4)&15, dq=tid&15;    // 8 dims/thread, head=dq>>2
        int qq=i2?q2:q1; bool pad=i2?pad2:pad1;
        int kend=pad?L_:qq+1;
        int k0=s16*16;
        int kmax=kend-k0; kmax=kmax<0?0:(kmax>16?16:kmax);
        const float* row=sS+(i2*4+(dq>>2))*256;
        const us16* tmrow=sTMu+i2*256;
        float a0=0,a1=0,a2=0,a3=0,a4=0,a5=0,a6=0,a7=0;
        for(int kk=0;kk<kmax;kk++){
            int kx=k0+kk;
            float aa=row[kx];
            int tmk=tmrow[kx];
            uint4 v4=((const uint4*)(Vb+(size_t)(b0+kx)*128))[dq];
            uint4 t4=((const uint4*)(a.tmV+(size_t)tmk*128))[dq];
            const us16* vu=(const us16*)&v4;
            const us16* tu=(const us16*)&t4;
            a0=fmaf(aa,us2f(vu[0])+us2f(tu[0]),a0);
            a1=fmaf(aa,us2f(vu[1])+us2f(tu[1]),a1);
            a2=fmaf(aa,us2f(vu[2])+us2f(tu[2]),a2);
            a3=fmaf(aa,us2f(vu[3])+us2f(tu[3]),a3);
            a4=fmaf(aa,us2f(vu[4])+us2f(tu[4]),a4);
            a5=fmaf(aa,us2f(vu[5])+us2f(tu[5]),a5);
            a6=fmaf(aa,us2f(vu[6])+us2f(tu[6]),a6);
            a7=fmaf(aa,us2f(vu[7])+us2f(tu[7]),a7);
        }
        float* dst=sPr+(i2*16+s16)*128+dq*8;
        ((float4*)dst)[0]=make_float4(a0,a1,a2,a3);
        ((float4*)dst)[1]=make_float4(a4,a5,a6,a7);
    }
    __syncthreads();

    // epilogue: +qin residual, LN2 -> sX (threads < 256 active; 2 waves per row)
    if(tid<256){
        int ii=tid>>7, l=tid&127;
        int rr = ii? r2:r1;
        float v=qin[(size_t)rr*128+l];
        #pragma unroll
        for(int sl=0;sl<16;sl++) v+=sPr[(ii*16+sl)*128+l];
        float s=v;
        #pragma unroll
        for(int o=32;o;o>>=1) s+=__shfl_xor(s,o,64);
        if((tid&63)==0) sRed[ii*2+((tid>>6)&1)]=s;
        __syncthreads();
        float m=(sRed[ii*2]+sRed[ii*2+1])*(1.f/128.f);
        float d=v-m;
        float vv=d*d;
        #pragma unroll
        for(int o=32;o;o>>=1) vv+=__shfl_xor(vv,o,64);
        if((tid&63)==0) sRed2[ii*2+((tid>>6)&1)]=vv;
        __syncthreads();
        float rstd=rsqrtf((sRed2[ii*2]+sRed2[ii*2+1])*(1.f/128.f)+1e-8f);
        sX[ii*128+l]=d*rstd*a.ln2g[layer*128+l]+a.ln2b[layer*128+l];
    } else { __syncthreads(); __syncthreads(); }
    __syncthreads();

    // tail: gemvs with out = tid&255 (ii,cc), kh = tid>>8; LDS partial combine.
    int out=tid&255, kh=tid>>8, ii=out>>7, cc=out&127;
    int rr = ii? r2:r1;
    int qown = ii? q2:q1;
    bool padown = ii? pad2:pad1;

    // FFN1: sH = relu(sX@W1 + b1)
    stage_w512(a.wsW+(size_t)(layer?5:0)*16384, sW, tid);
    __syncthreads();
    sPart[tid]=gemv_half(sW, sX+ii*128, kh, cc);
    __syncthreads();
    if(tid<256) sH[out]=fmaxf(sPart[tid]+sPart[tid+256]+a.b1[layer*128+cc],0.f);
    __syncthreads();
    // FFN2: f = sH@W2 + b2 + sX, mask
    stage_w512(a.wsW+(size_t)(layer?6:1)*16384, sW, tid);
    __syncthreads();
    sPart[tid]=gemv_half(sW, sH+ii*128, kh, cc);
    __syncthreads();
    float f=0.f;
    if(tid<256){
        f=sPart[tid]+sPart[tid+256]+a.b2[layer*128+cc]+sX[out];
        if(padown) f=0.f;
        sY[out]=f;
    }
    __syncthreads();

    if(layer==0){
        // LN1(L1) on f -> sX (Q input); raw f stays in sY (K,V input)
        if(tid<256){
            float s=f;
            #pragma unroll
            for(int o=32;o;o>>=1) s+=__shfl_xor(s,o,64);
            if((tid&63)==0) sRB[ii*2+((tid>>6)&1)]=s;
            __syncthreads();
            float m=(sRB[ii*2]+sRB[ii*2+1])*(1.f/128.f);
            float d=f-m;
            float vv=d*d;
            #pragma unroll
            for(int o=32;o;o>>=1) vv+=__shfl_xor(vv,o,64);
            if((tid&63)==0) sRB[4+ii*2+((tid>>6)&1)]=vv;
            __syncthreads();
            float rstd=rsqrtf((sRB[4+ii*2]+sRB[5+ii*2])*(1.f/128.f)+1e-8f);
            float y1=d*rstd*a.ln1g[128+cc]+a.ln1b[128+cc];
            a.qin1[(size_t)rr*128+cc]=y1;
            sX[out]=y1;
        } else { __syncthreads(); __syncthreads(); }
        __syncthreads();
        // Q(L1)
        stage_w512(a.wsW+(size_t)2*16384, sW, tid);
        __syncthreads();
        sPart[tid]=gemv_half(sW, sX+ii*128, kh, cc);
        __syncthreads();
        if(tid<256) a.Qb1[(size_t)rr*128+cc]=f2us(sPart[tid]+sPart[tid+256]+a.bq[128+cc]);
        __syncthreads();
        // K(L1)
        stage_w512(a.wsW+(size_t)3*16384, sW, tid);
        __syncthreads();
        sPart[tid]=gemv_half(sW, sY+ii*128, kh, cc);
        __syncthreads();
        if(tid<256) a.Kb1[(size_t)rr*128+cc]=f2us(sPart[tid]+sPart[tid+256]+a.bk[128+cc]+a.posK[qown*128+cc]);
        __syncthreads();
        // V(L1)
        stage_w512(a.wsW+(size_t)4*16384, sW, tid);
        __syncthreads();
        sPart[tid]=gemv_half(sW, sY+ii*128, kh, cc);
        __syncthreads();
        if(tid<256) a.Vb1[(size_t)rr*128+cc]=f2us(sPart[tid]+sPart[tid+256]+a.bv[128+cc]+a.posV[qown*128+cc]);
    } else {
        // LNf + logits
        if(tid<256){
            float s=f;
            #pragma unroll
            for(int o=32;o;o>>=1) s+=__shfl_xor(s,o,64);
            if((tid&63)==0) sRB[ii*2+((tid>>6)&1)]=s;
            __syncthreads();
            float m=(sRB[ii*2]+sRB[ii*2+1])*(1.f/128.f);
            float d=f-m;
            float vv=d*d;
            #pragma unroll
            for(int o=32;o;o>>=1) vv+=__shfl_xor(vv,o,64);
            if((tid&63)==0) sRB[4+ii*2+((tid>>6)&1)]=vv;
            __syncthreads();
            float rstd=rsqrtf((sRB[4+ii*2]+sRB[5+ii*2])*(1.f/128.f)+1e-8f);
            sX[out]=d*rstd*a.lnfg[cc]+a.lnfb[cc];
        } else { __syncthreads(); __syncthreads(); }
        __syncthreads();
        int w=tid>>6, lane=tid&63;
        if(w<4){
            int rowi=w>>1, neg=w&1;
            int rg = rowi? r2:r1;
            int id = neg? a.neg_seqs[rg] : a.pos_seqs[rg];
            const float* e=a.item_emb+(size_t)id*128;
            float s2 = sX[rowi*128+lane]*e[lane] + sX[rowi*128+lane+64]*e[lane+64];
            #pragma unroll
            for(int o=32;o;o>>=1) s2+=__shfl_xor(s2,o,64);
            if(lane==0) a.out[neg*ROWS+rg]=s2;
        }
    }
}

extern "C" void kernel_launch(void* const* d_in, const int* in_sizes, int n_in,
                              void* d_out, int out_size, void* d_ws, size_t ws_size,
                              hipStream_t stream) {
    KArgs a;
    a.log_seqs=(const int*)d_in[1];
    a.tmat    =(const int*)d_in[2];
    a.pos_seqs=(const int*)d_in[3];
    a.neg_seqs=(const int*)d_in[4];
    a.item_emb=(const float*)d_in[5];
    a.posK =(const float*)d_in[6];
    a.posV =(const float*)d_in[7];
    a.timeK=(const float*)d_in[8];
    a.timeV=(const float*)d_in[9];
    a.ln1g=(const float*)d_in[10];
    a.ln1b=(const float*)d_in[11];
    a.Wq=(const float*)d_in[12];
    a.bq=(const float*)d_in[13];
    a.Wk=(const float*)d_in[14];
    a.bk=(const float*)d_in[15];
    a.Wv=(const float*)d_in[16];
    a.bv=(const float*)d_in[17];
    a.ln2g=(const float*)d_in[18];
    a.ln2b=(const float*)d_in[19];
    a.W1=(const float*)d_in[20];
    a.b1=(const float*)d_in[21];
    a.W2=(const float*)d_in[22];
    a.b2=(const float*)d_in[23];
    a.lnfg=(const float*)d_in[24];
    a.lnfb=(const float*)d_in[25];

    const size_t MB=1u<<20;
    char* w=(char*)d_ws;
    a.qin0=(float*)(w+0*MB);
    a.qin1=(float*)(w+1*MB);
    a.Qb0 =(us16*) (w+2*MB);
    a.Kb0 =(us16*) (w+2*MB+512*1024);
    a.Vb0 =(us16*) (w+3*MB);
    a.Qb1 =(us16*) (w+3*MB+512*1024);
    a.Kb1 =(us16*) (w+4*MB);
    a.Vb1 =(us16*) (w+4*MB+512*1024);
    a.wsW =(us16*) (w+5*MB);              // 7 x 32KB, k-major
    a.tmK =(us16*) (w+5*MB+256*1024);     // 65792 B
    a.tmV =(us16*) (w+5*MB+384*1024);
    a.out =(float*)d_out;

    k_pre<<<946,256,0,stream>>>(a);
    k_blk<<<1024,512,0,stream>>>(a,0);
    k_blk<<<1024,512,0,stream>>>(a,1);
}